// Round 3
// baseline (427.627 us; speedup 1.0000x reference)
//
#include <hip/hip_runtime.h>
#include <math.h>

#define D 128
#define THREADS 256

// ---------------------------------------------------------------------------
// Phase 1: one-pass linked-list build + degree count.
//   next[e] = atomicExch(&head[dst[e]], e)   (coalesced write to next[])
//   deg[dst[e]]++ for the norm factor.
// Replaces the old k_deg + 3-kernel scan + k_place (which paid 105MB of
// scattered 4B write-allocate traffic).
// ---------------------------------------------------------------------------
__global__ __launch_bounds__(THREADS) void k_build(
    const int* __restrict__ dst, int* __restrict__ deg,
    int* __restrict__ head, int* __restrict__ nxt, int E) {
    int e = blockIdx.x * THREADS + threadIdx.x;
    if (e < E) {
        int d = dst[e];
        atomicAdd(&deg[d], 1);
        nxt[e] = atomicExch(&head[d], e);   // coalesced store
    }
}

// ---------------------------------------------------------------------------
// Phase 2: norm = rsqrt(max(deg,1))
// ---------------------------------------------------------------------------
__global__ __launch_bounds__(THREADS) void k_norm(const int* __restrict__ degc,
                                                  float* __restrict__ normf, int n) {
    int i = blockIdx.x * THREADS + threadIdx.x;
    if (i < n) normf[i] = rsqrtf(fmaxf((float)degc[i], 1.0f));
}

// ---------------------------------------------------------------------------
// Phase 3: gather-aggregate via chain walk. 32 lanes per node, float4/lane.
// Per hop: nxt[cur]/src[cur]/normf[s] are same-address across the group
// (hardware broadcast); the 512B feature row read is coalesced. Chain
// latency (~16 hops x ~300cy) hides under 64 concurrent chains/CU since the
// kernel is BW-bound. Single row write of t = 0.9*agg*norm + 0.1*init.
// ---------------------------------------------------------------------------
__global__ __launch_bounds__(THREADS) void k_agg(
    const float* __restrict__ features, const float* __restrict__ initf,
    const int* __restrict__ head, const int* __restrict__ nxt,
    const int* __restrict__ srcA, const float* __restrict__ normf,
    float* __restrict__ out, int n) {
    int g = (blockIdx.x * THREADS + threadIdx.x) >> 5;
    if (g >= n) return;
    const int lane = threadIdx.x & 31;

    float4 acc = {0.f, 0.f, 0.f, 0.f};
    int cur = head[g];
    while (cur >= 0) {
        int nx = nxt[cur];            // dependent load — issue first
        int s  = srcA[cur];
        float w = normf[s];
        float4 f = ((const float4*)(features + (size_t)s * D))[lane];
        acc.x += f.x * w; acc.y += f.y * w; acc.z += f.z * w; acc.w += f.w * w;
        cur = nx;
    }

    const float nv = normf[g];
    float4 iv = ((const float4*)(initf + (size_t)g * D))[lane];
    float4 t;
    t.x = 0.9f * (acc.x * nv) + 0.1f * iv.x;
    t.y = 0.9f * (acc.y * nv) + 0.1f * iv.y;
    t.z = 0.9f * (acc.z * nv) + 0.1f * iv.z;
    t.w = 0.9f * (acc.w * nv) + 0.1f * iv.w;
    ((float4*)(out + (size_t)g * D))[lane] = t;
}

// ---------------------------------------------------------------------------
// Phase 4: out = relu(0.5*t + 0.5*(t @ W^T)), t read from `out` in place.
// LDS: Wt[k][j] = W[j][k] (64KB, row reads bank-spread) + T[k][n] (16KB)
// = 81920B total -> 2 blocks/CU. 4 nodes x 4 cols per thread.
// ---------------------------------------------------------------------------
__global__ __launch_bounds__(THREADS, 2) void k_final(
    const float* __restrict__ W, float* __restrict__ out, int n) {
    __shared__ float Wt[D * D];   // [k][j]
    __shared__ float T[D * 32];   // [k][node-in-group]
    const int tid = threadIdx.x;

    for (int i = tid; i < D * D; i += THREADS) {
        int j = i >> 7, k = i & (D - 1);
        Wt[k * D + j] = W[i];
    }

    const int jv = tid & 31;       // column-quad index
    const int ng = tid >> 5;       // node-quad index
    const int j0 = jv * 4;
    const int n0 = ng * 4;
    const int sn = tid >> 3;       // staging: node 0..31
    const int sv0 = (tid & 7) * 4; // staging: float4 index base 0..28

    const int numGroups = (n + 31) >> 5;
    for (int g = blockIdx.x; g < numGroups; g += gridDim.x) {
        const int base = g << 5;
        __syncthreads();  // protect T from previous iteration's readers
        {
            const int node = base + sn;
            if (node < n) {
                const float4* tg = (const float4*)(out + (size_t)node * D);
#pragma unroll
                for (int q = 0; q < 4; ++q) {
                    const int v4 = sv0 + q;
                    float4 a4 = tg[v4];
                    const int k = v4 * 4;
                    T[(k + 0) * 32 + sn] = a4.x;
                    T[(k + 1) * 32 + sn] = a4.y;
                    T[(k + 2) * 32 + sn] = a4.z;
                    T[(k + 3) * 32 + sn] = a4.w;
                }
            } else {
#pragma unroll
                for (int q = 0; q < 4; ++q) {
                    const int k = (sv0 + q) * 4;
                    T[(k + 0) * 32 + sn] = 0.0f;
                    T[(k + 1) * 32 + sn] = 0.0f;
                    T[(k + 2) * 32 + sn] = 0.0f;
                    T[(k + 3) * 32 + sn] = 0.0f;
                }
            }
        }
        __syncthreads();

        float acc[4][4];
#pragma unroll
        for (int a = 0; a < 4; ++a)
#pragma unroll
            for (int b = 0; b < 4; ++b) acc[a][b] = 0.0f;

#pragma unroll 8
        for (int k = 0; k < D; ++k) {
            const float4 t4 = *(const float4*)&T[k * 32 + n0];
            const float4 w4 = *(const float4*)&Wt[k * D + j0];
            acc[0][0] += t4.x * w4.x; acc[0][1] += t4.x * w4.y;
            acc[0][2] += t4.x * w4.z; acc[0][3] += t4.x * w4.w;
            acc[1][0] += t4.y * w4.x; acc[1][1] += t4.y * w4.y;
            acc[1][2] += t4.y * w4.z; acc[1][3] += t4.y * w4.w;
            acc[2][0] += t4.z * w4.x; acc[2][1] += t4.z * w4.y;
            acc[2][2] += t4.z * w4.z; acc[2][3] += t4.z * w4.w;
            acc[3][0] += t4.w * w4.x; acc[3][1] += t4.w * w4.y;
            acc[3][2] += t4.w * w4.z; acc[3][3] += t4.w * w4.w;
        }

#pragma unroll
        for (int a = 0; a < 4; ++a) {
            const int node = base + n0 + a;
            if (node < n) {
                const float t0 = T[(j0 + 0) * 32 + n0 + a];
                const float t1 = T[(j0 + 1) * 32 + n0 + a];
                const float t2 = T[(j0 + 2) * 32 + n0 + a];
                const float t3 = T[(j0 + 3) * 32 + n0 + a];
                float4 r;
                r.x = fmaxf(0.5f * t0 + 0.5f * acc[a][0], 0.0f);
                r.y = fmaxf(0.5f * t1 + 0.5f * acc[a][1], 0.0f);
                r.z = fmaxf(0.5f * t2 + 0.5f * acc[a][2], 0.0f);
                r.w = fmaxf(0.5f * t3 + 0.5f * acc[a][3], 0.0f);
                *(float4*)(out + (size_t)node * D + j0) = r;
            }
        }
    }
}

// ---------------------------------------------------------------------------
extern "C" void kernel_launch(void* const* d_in, const int* in_sizes, int n_in,
                              void* d_out, int out_size, void* d_ws, size_t ws_size,
                              hipStream_t stream) {
    const float* features = (const float*)d_in[0];
    const float* initf    = (const float*)d_in[1];
    const float* W        = (const float*)d_in[2];
    const int*   src      = (const int*)d_in[3];
    const int*   dst      = (const int*)d_in[4];
    float* out = (float*)d_out;

    const int n = in_sizes[0] / D;
    const int E = in_sizes[3];
    if (n <= 0) return;

    // workspace layout (3n + E ints ~= 7.6 MB, same footprint as round 2)
    int*   deg   = (int*)d_ws;           // [n]
    int*   head  = deg + n;              // [n]
    float* normf = (float*)(head + n);   // [n]
    int*   nxt   = (int*)(normf + n);    // [E]

    hipMemsetAsync(deg, 0, (size_t)n * sizeof(int), stream);
    hipMemsetAsync(head, 0xFF, (size_t)n * sizeof(int), stream);  // head = -1

    k_build<<<(E + THREADS - 1) / THREADS, THREADS, 0, stream>>>(dst, deg, head, nxt, E);
    k_norm<<<(n + THREADS - 1) / THREADS, THREADS, 0, stream>>>(deg, normf, n);

    const int agg_total = n * 32;  // 32 lanes per node
    k_agg<<<(agg_total + THREADS - 1) / THREADS, THREADS, 0, stream>>>(
        features, initf, head, nxt, src, normf, out, n);

    k_final<<<512, THREADS, 0, stream>>>(W, out, n);
}

// Round 5
// 320.534 us; speedup vs baseline: 1.3341x; 1.3341x over previous
//
#include <hip/hip_runtime.h>
#include <math.h>

#define D 128
#define THREADS 256

typedef __attribute__((ext_vector_type(8))) short s16x8;   // 8 bf16 (4 VGPR)
typedef __attribute__((ext_vector_type(4))) float f32x4;   // MFMA acc

__device__ __forceinline__ unsigned short f2bf(float f) {  // RNE float->bf16
    unsigned u = __float_as_uint(f);
    u += 0x7FFFu + ((u >> 16) & 1u);
    return (unsigned short)(u >> 16);
}
__device__ __forceinline__ float bflo(unsigned u) { return __uint_as_float(u << 16); }
__device__ __forceinline__ float bfhi(unsigned u) { return __uint_as_float(u & 0xFFFF0000u); }

// ---------------------------------------------------------------------------
// Phase 1: linked-list build + degree. p[e] = {next, src} packed int2 so the
// chain walk touches ONE 64B line per hop instead of two.
// ---------------------------------------------------------------------------
__global__ __launch_bounds__(THREADS) void k_build(
    const int* __restrict__ src, const int* __restrict__ dst,
    int* __restrict__ deg, int* __restrict__ head, int2* __restrict__ p, int E) {
    int e = blockIdx.x * THREADS + threadIdx.x;
    if (e < E) {
        int d = dst[e];
        atomicAdd(&deg[d], 1);
        int nx = atomicExch(&head[d], e);
        p[e] = make_int2(nx, src[e]);   // coalesced 8B store
    }
}

// ---------------------------------------------------------------------------
// Phase 2: norm = rsqrt(max(deg,1)), in place (int -> float, same buffer)
// ---------------------------------------------------------------------------
__global__ __launch_bounds__(THREADS) void k_norm(const int* __restrict__ degc,
                                                  float* __restrict__ normf, int n) {
    int i = blockIdx.x * THREADS + threadIdx.x;
    if (i < n) {
        float d = (float)degc[i];
        normf[i] = rsqrtf(fmaxf(d, 1.0f));
    }
}

// ---------------------------------------------------------------------------
// Phase 3: hb[i][k] = bf16(features[i][k] * norm[i]) — premultiplied bf16 rows
// halve gather traffic AND remove the scattered normf[src] lookup.
// ---------------------------------------------------------------------------
__global__ __launch_bounds__(THREADS) void k_scale(
    const float* __restrict__ f, const float* __restrict__ nrm,
    uint4* __restrict__ hb, int n) {
    int c = blockIdx.x * THREADS + threadIdx.x;  // one 8-float chunk
    if (c >= n * 16) return;
    float nv = nrm[c >> 4];
    const float4* fp = (const float4*)f;
    float4 a = fp[c * 2], b = fp[c * 2 + 1];
    uint4 o;
    o.x = f2bf(a.x * nv) | ((unsigned)f2bf(a.y * nv) << 16);
    o.y = f2bf(a.z * nv) | ((unsigned)f2bf(a.w * nv) << 16);
    o.z = f2bf(b.x * nv) | ((unsigned)f2bf(b.y * nv) << 16);
    o.w = f2bf(b.z * nv) | ((unsigned)f2bf(b.w * nv) << 16);
    hb[c] = o;
}

// ---------------------------------------------------------------------------
// Phase 4 (fused): per 32-node tile: chain-gather t = 0.9*norm*agg + 0.1*init
// into XOR-swizzled LDS (bf16), then out = relu(t @ M^T) via MFMA, where
// M[j][k] = 0.5*W[j][k] + 0.5*(j==k) folds the identity-residual into the GEMM.
// LDS = 32KB (M) + 8KB (T) -> 4 blocks/CU -> 64 concurrent chains/CU.
// Swizzle: 16B-chunk index c stored at (c ^ (row&7)) — frag reads 2-way (free).
// mfma_f32_16x16x32_bf16 layouts: A row=lane&15, k=(lane>>4)*8+j;
// B col=lane&15, same k; D col=lane&15, row=(lane>>4)*4+reg (m89-verified).
// ---------------------------------------------------------------------------
template <int BF>
__global__ __launch_bounds__(THREADS) void k_fused(
    const uint4* __restrict__ hb, const float* __restrict__ features,
    const float* __restrict__ initf, const int* __restrict__ head,
    const int2* __restrict__ p, const float* __restrict__ normf,
    const float* __restrict__ W, float* __restrict__ out, int n, int numTiles) {

    __shared__ uint4 sMt[D * 16];   // 32 KB: M[j][k] bf16, swizzled
    __shared__ uint4 sT[32 * 16];   // 8 KB: t[node][k] bf16, swizzled

    const int tid = threadIdx.x;

    // ---- stage M once per block: D rows x 16 chunks of 8 bf16 ----
    // (round-4 bug: loop ran c < D*8 / kc = c&7, leaving chunks 8..15 of
    //  every row as uninitialized LDS -> inf through the MFMA B-operand)
    for (int c = tid; c < D * 16; c += THREADS) {
        const int j = c >> 4, kc = c & 15;
        const float* wr = W + j * D + kc * 8;
        float m[8];
#pragma unroll
        for (int q = 0; q < 8; ++q) m[q] = 0.5f * wr[q];
        const int dj = j - kc * 8;
        if (dj >= 0 && dj < 8) m[dj] += 0.5f;   // + 0.5*I (kc == j>>3 chunk)
        uint4 o;
        o.x = f2bf(m[0]) | ((unsigned)f2bf(m[1]) << 16);
        o.y = f2bf(m[2]) | ((unsigned)f2bf(m[3]) << 16);
        o.z = f2bf(m[4]) | ((unsigned)f2bf(m[5]) << 16);
        o.w = f2bf(m[6]) | ((unsigned)f2bf(m[7]) << 16);
        sMt[j * 16 + (kc ^ (j & 7))] = o;
    }
    __syncthreads();

    const int gi = tid >> 4, gl = tid & 15;          // gather: 16 groups x 16 lanes
    const int wave = tid >> 6, lane = tid & 63;      // gemm ids
    const int l15 = lane & 15, lq = lane >> 4;
    const int mt = wave & 1, ntb = (wave >> 1) * 4;

    for (int tile = blockIdx.x; tile < numTiles; tile += gridDim.x) {
        const int base = tile << 5;

        // ---- gather: each 16-lane group walks 2 node chains ----
#pragma unroll
        for (int s = 0; s < 2; ++s) {
            const int ni = gi * 2 + s;
            const int node = base + ni;
            float t[8];
            if (node < n) {
                float acc[8] = {0.f, 0.f, 0.f, 0.f, 0.f, 0.f, 0.f, 0.f};
                int cur = head[node];
                while (cur >= 0) {
                    const int2 pc = p[cur];          // {next, src} one line
                    if (BF) {
                        const uint4 r = hb[(size_t)pc.y * 16 + gl];  // 256B row
                        acc[0] += bflo(r.x); acc[1] += bfhi(r.x);
                        acc[2] += bflo(r.y); acc[3] += bfhi(r.y);
                        acc[4] += bflo(r.z); acc[5] += bfhi(r.z);
                        acc[6] += bflo(r.w); acc[7] += bfhi(r.w);
                    } else {
                        const float w = normf[pc.y];
                        const float4* fr = (const float4*)(features + (size_t)pc.y * D);
                        const float4 f0 = fr[gl * 2], f1 = fr[gl * 2 + 1];
                        acc[0] += f0.x * w; acc[1] += f0.y * w;
                        acc[2] += f0.z * w; acc[3] += f0.w * w;
                        acc[4] += f1.x * w; acc[5] += f1.y * w;
                        acc[6] += f1.z * w; acc[7] += f1.w * w;
                    }
                    cur = pc.x;
                }
                const float nv = 0.9f * normf[node];
                const float4* iv = (const float4*)(initf + (size_t)node * D);
                const float4 i0 = iv[gl * 2], i1 = iv[gl * 2 + 1];
                t[0] = nv * acc[0] + 0.1f * i0.x; t[1] = nv * acc[1] + 0.1f * i0.y;
                t[2] = nv * acc[2] + 0.1f * i0.z; t[3] = nv * acc[3] + 0.1f * i0.w;
                t[4] = nv * acc[4] + 0.1f * i1.x; t[5] = nv * acc[5] + 0.1f * i1.y;
                t[6] = nv * acc[6] + 0.1f * i1.z; t[7] = nv * acc[7] + 0.1f * i1.w;
            } else {
#pragma unroll
                for (int q = 0; q < 8; ++q) t[q] = 0.f;
            }
            uint4 o;
            o.x = f2bf(t[0]) | ((unsigned)f2bf(t[1]) << 16);
            o.y = f2bf(t[2]) | ((unsigned)f2bf(t[3]) << 16);
            o.z = f2bf(t[4]) | ((unsigned)f2bf(t[5]) << 16);
            o.w = f2bf(t[6]) | ((unsigned)f2bf(t[7]) << 16);
            sT[ni * 16 + (gl ^ (ni & 7))] = o;
        }
        __syncthreads();

        // ---- GEMM: out[tile] = relu(T @ M^T), 16 MFMA per wave ----
        const int nr = mt * 16 + l15;
        s16x8 a[4];
#pragma unroll
        for (int ks = 0; ks < 4; ++ks)
            a[ks] = *reinterpret_cast<const s16x8*>(
                &sT[nr * 16 + ((ks * 4 + lq) ^ (nr & 7))]);

#pragma unroll
        for (int tnt = 0; tnt < 4; ++tnt) {
            const int nt = ntb + tnt;
            const int jr = nt * 16 + l15;
            f32x4 c = {0.f, 0.f, 0.f, 0.f};
#pragma unroll
            for (int ks = 0; ks < 4; ++ks) {
                const s16x8 b = *reinterpret_cast<const s16x8*>(
                    &sMt[jr * 16 + ((ks * 4 + lq) ^ (jr & 7))]);
                c = __builtin_amdgcn_mfma_f32_16x16x32_bf16(a[ks], b, c, 0, 0, 0);
            }
            const int col = nt * 16 + l15;
            const int row0 = base + mt * 16 + lq * 4;
#pragma unroll
            for (int r = 0; r < 4; ++r) {
                const int node = row0 + r;
                if (node < n) out[(size_t)node * D + col] = fmaxf(c[r], 0.f);
            }
        }
        __syncthreads();   // sT reused next tile
    }
}

// ---------------------------------------------------------------------------
extern "C" void kernel_launch(void* const* d_in, const int* in_sizes, int n_in,
                              void* d_out, int out_size, void* d_ws, size_t ws_size,
                              hipStream_t stream) {
    const float* features = (const float*)d_in[0];
    const float* initf    = (const float*)d_in[1];
    const float* W        = (const float*)d_in[2];
    const int*   src      = (const int*)d_in[3];
    const int*   dst      = (const int*)d_in[4];
    float* out = (float*)d_out;

    const int n = in_sizes[0] / D;
    const int E = in_sizes[3];
    if (n <= 0) return;

    // workspace layout (16B-aligned slots)
    const size_t nA = ((size_t)n * 4 + 15) & ~(size_t)15;
    const size_t pA = ((size_t)E * 8 + 15) & ~(size_t)15;
    int*   buf0 = (int*)d_ws;                         // deg -> normf (aliased)
    int*   head = (int*)((char*)d_ws + nA);           // [n]
    int2*  p    = (int2*)((char*)d_ws + 2 * nA);      // [E] {next, src}
    uint4* hb   = (uint4*)((char*)d_ws + 2 * nA + pA);// [n*16] bf16 rows
    float* normf = (float*)buf0;

    const size_t need_bf = 2 * nA + pA + (size_t)n * 256;
    const bool BF = (ws_size >= need_bf);

    hipMemsetAsync(buf0, 0, (size_t)n * 4, stream);
    hipMemsetAsync(head, 0xFF, (size_t)n * 4, stream);

    k_build<<<(E + THREADS - 1) / THREADS, THREADS, 0, stream>>>(src, dst, buf0, head, p, E);
    k_norm<<<(n + THREADS - 1) / THREADS, THREADS, 0, stream>>>(buf0, normf, n);

    const int numTiles = (n + 31) >> 5;
    const int grid = numTiles < 1024 ? numTiles : 1024;  // 4 blocks/CU

    if (BF) {
        k_scale<<<(n * 16 + THREADS - 1) / THREADS, THREADS, 0, stream>>>(
            features, normf, hb, n);
        k_fused<1><<<grid, THREADS, 0, stream>>>(hb, features, initf, head, p,
                                                 normf, W, out, n, numTiles);
    } else {
        k_fused<0><<<grid, THREADS, 0, stream>>>(hb, features, initf, head, p,
                                                 normf, W, out, n, numTiles);
    }
}

// Round 6
// 285.891 us; speedup vs baseline: 1.4958x; 1.1212x over previous
//
#include <hip/hip_runtime.h>
#include <math.h>

#define D 128
#define THREADS 256

typedef __attribute__((ext_vector_type(8))) short s16x8;   // 8 bf16 (4 VGPR)
typedef __attribute__((ext_vector_type(4))) float f32x4;   // MFMA acc

__device__ __forceinline__ unsigned short f2bf(float f) {  // RNE float->bf16
    unsigned u = __float_as_uint(f);
    u += 0x7FFFu + ((u >> 16) & 1u);
    return (unsigned short)(u >> 16);
}
__device__ __forceinline__ float bflo(unsigned u) { return __uint_as_float(u << 16); }
__device__ __forceinline__ float bfhi(unsigned u) { return __uint_as_float(u & 0xFFFF0000u); }

// ---------------------------------------------------------------------------
// Phase 1: linked-list build, ONE atomic per edge (exch only; deg is counted
// later by walking). WAYS independent chains per node -> WAYS-way MLP in all
// walks. p[e] = {next, src} packed so a hop touches one 64B line.
// ---------------------------------------------------------------------------
template <int WAYS>
__global__ __launch_bounds__(THREADS) void k_build(
    const int* __restrict__ src, const int* __restrict__ dst,
    int* __restrict__ head, int2* __restrict__ p, int E) {
    int e = blockIdx.x * THREADS + threadIdx.x;
    if (e < E) {
        int d = dst[e];
        int nx = atomicExch(&head[(size_t)d * WAYS + (e & (WAYS - 1))], e);
        p[e] = make_int2(nx, src[e]);   // coalesced 8B store
    }
}

// ---------------------------------------------------------------------------
// Phase 2: deg by chain-length count (replaces the 1.6M-atomic k_deg) +
// norm = rsqrt(max(deg,1)). One thread per node, WAYS chains interleaved.
// ---------------------------------------------------------------------------
template <int WAYS>
__global__ __launch_bounds__(THREADS) void k_normwalk(
    const int* __restrict__ head, const int2* __restrict__ p,
    float* __restrict__ normf, int n) {
    int i = blockIdx.x * THREADS + threadIdx.x;
    if (i >= n) return;
    int c[WAYS];
#pragma unroll
    for (int w = 0; w < WAYS; ++w) c[w] = head[(size_t)i * WAYS + w];
    int cnt = 0;
    bool any = false;
#pragma unroll
    for (int w = 0; w < WAYS; ++w) any |= (c[w] >= 0);
    while (any) {
        any = false;
#pragma unroll
        for (int w = 0; w < WAYS; ++w) {
            if (c[w] >= 0) {
                ++cnt;
                c[w] = p[c[w]].x;
                any |= (c[w] >= 0);
            }
        }
    }
    normf[i] = rsqrtf(fmaxf((float)cnt, 1.0f));
}

// ---------------------------------------------------------------------------
// Phase 3: hb[i][k] = bf16(features[i][k] * norm[i]) — premultiplied bf16 rows
// ---------------------------------------------------------------------------
__global__ __launch_bounds__(THREADS) void k_scale(
    const float* __restrict__ f, const float* __restrict__ nrm,
    uint4* __restrict__ hb, int n) {
    int c = blockIdx.x * THREADS + threadIdx.x;  // one 8-float chunk
    if (c >= n * 16) return;
    float nv = nrm[c >> 4];
    const float4* fp = (const float4*)f;
    float4 a = fp[c * 2], b = fp[c * 2 + 1];
    uint4 o;
    o.x = f2bf(a.x * nv) | ((unsigned)f2bf(a.y * nv) << 16);
    o.y = f2bf(a.z * nv) | ((unsigned)f2bf(a.w * nv) << 16);
    o.z = f2bf(b.x * nv) | ((unsigned)f2bf(b.y * nv) << 16);
    o.w = f2bf(b.z * nv) | ((unsigned)f2bf(b.w * nv) << 16);
    hb[c] = o;
}

// ---------------------------------------------------------------------------
// Phase 4 (fused): per 32-node tile: chain-gather t into swizzled LDS (bf16),
// then out = relu(t @ M^T) via MFMA, M = 0.5*W + 0.5*I.
// Gather walks the node's WAYS chains interleaved (WAYS outstanding p-loads +
// rows) to hide the pointer-chase latency. LDS 40KB -> 4 blocks/CU.
// ---------------------------------------------------------------------------
template <int WAYS, int BF>
__global__ __launch_bounds__(THREADS) void k_fused(
    const uint4* __restrict__ hb, const float* __restrict__ features,
    const float* __restrict__ initf, const int* __restrict__ head,
    const int2* __restrict__ p, const float* __restrict__ normf,
    const float* __restrict__ W, float* __restrict__ out, int n, int numTiles) {

    __shared__ uint4 sMt[D * 16];   // 32 KB: M[j][k] bf16, swizzled
    __shared__ uint4 sT[32 * 16];   // 8 KB: t[node][k] bf16, swizzled

    const int tid = threadIdx.x;

    // ---- stage M once per block: D rows x 16 chunks of 8 bf16 ----
    for (int c = tid; c < D * 16; c += THREADS) {
        const int j = c >> 4, kc = c & 15;
        const float* wr = W + j * D + kc * 8;
        float m[8];
#pragma unroll
        for (int q = 0; q < 8; ++q) m[q] = 0.5f * wr[q];
        const int dj = j - kc * 8;
        if (dj >= 0 && dj < 8) m[dj] += 0.5f;   // + 0.5*I
        uint4 o;
        o.x = f2bf(m[0]) | ((unsigned)f2bf(m[1]) << 16);
        o.y = f2bf(m[2]) | ((unsigned)f2bf(m[3]) << 16);
        o.z = f2bf(m[4]) | ((unsigned)f2bf(m[5]) << 16);
        o.w = f2bf(m[6]) | ((unsigned)f2bf(m[7]) << 16);
        sMt[j * 16 + (kc ^ (j & 7))] = o;
    }
    __syncthreads();

    const int gi = tid >> 4, gl = tid & 15;          // gather: 16 groups x 16 lanes
    const int wave = tid >> 6, lane = tid & 63;      // gemm ids
    const int l15 = lane & 15, lq = lane >> 4;
    const int mt = wave & 1, ntb = (wave >> 1) * 4;

    for (int tile = blockIdx.x; tile < numTiles; tile += gridDim.x) {
        const int base = tile << 5;

        // ---- gather: each 16-lane group walks 2 nodes' chain bundles ----
#pragma unroll
        for (int s = 0; s < 2; ++s) {
            const int ni = gi * 2 + s;
            const int node = base + ni;
            float t[8];
            if (node < n) {
                const float nv = 0.9f * normf[node];
                const float4* iv = (const float4*)(initf + (size_t)node * D);
                const float4 i0 = iv[gl * 2], i1 = iv[gl * 2 + 1];
                float acc[8] = {0.f, 0.f, 0.f, 0.f, 0.f, 0.f, 0.f, 0.f};
                int c[WAYS];
#pragma unroll
                for (int w = 0; w < WAYS; ++w) c[w] = head[(size_t)node * WAYS + w];
                bool any = false;
#pragma unroll
                for (int w = 0; w < WAYS; ++w) any |= (c[w] >= 0);
                while (any) {
                    int2 pc[WAYS];
#pragma unroll
                    for (int w = 0; w < WAYS; ++w)    // issue all p-loads first
                        if (c[w] >= 0) pc[w] = p[c[w]];
                    any = false;
#pragma unroll
                    for (int w = 0; w < WAYS; ++w) {
                        if (c[w] >= 0) {
                            if (BF) {
                                const uint4 r = hb[(size_t)pc[w].y * 16 + gl];
                                acc[0] += bflo(r.x); acc[1] += bfhi(r.x);
                                acc[2] += bflo(r.y); acc[3] += bfhi(r.y);
                                acc[4] += bflo(r.z); acc[5] += bfhi(r.z);
                                acc[6] += bflo(r.w); acc[7] += bfhi(r.w);
                            } else {
                                const float ww = normf[pc[w].y];
                                const float4* fr =
                                    (const float4*)(features + (size_t)pc[w].y * D);
                                const float4 f0 = fr[gl * 2], f1 = fr[gl * 2 + 1];
                                acc[0] += f0.x * ww; acc[1] += f0.y * ww;
                                acc[2] += f0.z * ww; acc[3] += f0.w * ww;
                                acc[4] += f1.x * ww; acc[5] += f1.y * ww;
                                acc[6] += f1.z * ww; acc[7] += f1.w * ww;
                            }
                            c[w] = pc[w].x;
                            any |= (c[w] >= 0);
                        }
                    }
                }
                t[0] = nv * acc[0] + 0.1f * i0.x; t[1] = nv * acc[1] + 0.1f * i0.y;
                t[2] = nv * acc[2] + 0.1f * i0.z; t[3] = nv * acc[3] + 0.1f * i0.w;
                t[4] = nv * acc[4] + 0.1f * i1.x; t[5] = nv * acc[5] + 0.1f * i1.y;
                t[6] = nv * acc[6] + 0.1f * i1.z; t[7] = nv * acc[7] + 0.1f * i1.w;
            } else {
#pragma unroll
                for (int q = 0; q < 8; ++q) t[q] = 0.f;
            }
            uint4 o;
            o.x = f2bf(t[0]) | ((unsigned)f2bf(t[1]) << 16);
            o.y = f2bf(t[2]) | ((unsigned)f2bf(t[3]) << 16);
            o.z = f2bf(t[4]) | ((unsigned)f2bf(t[5]) << 16);
            o.w = f2bf(t[6]) | ((unsigned)f2bf(t[7]) << 16);
            sT[ni * 16 + (gl ^ (ni & 7))] = o;
        }
        __syncthreads();

        // ---- GEMM: out[tile] = relu(T @ M^T), 16 MFMA per wave ----
        const int nr = mt * 16 + l15;
        s16x8 a[4];
#pragma unroll
        for (int ks = 0; ks < 4; ++ks)
            a[ks] = *reinterpret_cast<const s16x8*>(
                &sT[nr * 16 + ((ks * 4 + lq) ^ (nr & 7))]);

#pragma unroll
        for (int tnt = 0; tnt < 4; ++tnt) {
            const int nt = ntb + tnt;
            const int jr = nt * 16 + l15;
            f32x4 c = {0.f, 0.f, 0.f, 0.f};
#pragma unroll
            for (int ks = 0; ks < 4; ++ks) {
                const s16x8 b = *reinterpret_cast<const s16x8*>(
                    &sMt[jr * 16 + ((ks * 4 + lq) ^ (jr & 7))]);
                c = __builtin_amdgcn_mfma_f32_16x16x32_bf16(a[ks], b, c, 0, 0, 0);
            }
            const int col = nt * 16 + l15;
            const int row0 = base + mt * 16 + lq * 4;
#pragma unroll
            for (int r = 0; r < 4; ++r) {
                const int node = row0 + r;
                if (node < n) out[(size_t)node * D + col] = fmaxf(c[r], 0.f);
            }
        }
        __syncthreads();   // sT reused next tile
    }
}

// ---------------------------------------------------------------------------
template <int WAYS, int BF>
static void run_all(const float* features, const float* initf, const float* W,
                    const int* src, const int* dst, float* out, void* d_ws,
                    int n, int E, hipStream_t stream) {
    const size_t nA = ((size_t)n * 4 + 15) & ~(size_t)15;
    const size_t pA = ((size_t)E * 8 + 15) & ~(size_t)15;
    float* normf = (float*)d_ws;
    int*   head  = (int*)((char*)d_ws + nA);
    int2*  p     = (int2*)((char*)d_ws + nA + (size_t)WAYS * nA);
    uint4* hb    = (uint4*)((char*)d_ws + nA + (size_t)WAYS * nA + pA);

    hipMemsetAsync(head, 0xFF, (size_t)WAYS * n * 4, stream);  // head = -1

    k_build<WAYS><<<(E + THREADS - 1) / THREADS, THREADS, 0, stream>>>(
        src, dst, head, p, E);
    k_normwalk<WAYS><<<(n + THREADS - 1) / THREADS, THREADS, 0, stream>>>(
        head, p, normf, n);
    if (BF)
        k_scale<<<(n * 16 + THREADS - 1) / THREADS, THREADS, 0, stream>>>(
            features, normf, hb, n);

    const int numTiles = (n + 31) >> 5;
    const int grid = numTiles < 1024 ? numTiles : 1024;  // 4 blocks/CU (40KB LDS)
    k_fused<WAYS, BF><<<grid, THREADS, 0, stream>>>(
        hb, features, initf, head, p, normf, W, out, n, numTiles);
}

extern "C" void kernel_launch(void* const* d_in, const int* in_sizes, int n_in,
                              void* d_out, int out_size, void* d_ws, size_t ws_size,
                              hipStream_t stream) {
    const float* features = (const float*)d_in[0];
    const float* initf    = (const float*)d_in[1];
    const float* W        = (const float*)d_in[2];
    const int*   src      = (const int*)d_in[3];
    const int*   dst      = (const int*)d_in[4];
    float* out = (float*)d_out;

    const int n = in_sizes[0] / D;
    const int E = in_sizes[3];
    if (n <= 0) return;

    const size_t nA = ((size_t)n * 4 + 15) & ~(size_t)15;
    const size_t pA = ((size_t)E * 8 + 15) & ~(size_t)15;
    const size_t hbA = (size_t)n * 256;
    auto need = [&](int ways, bool bf) {
        return nA + (size_t)ways * nA + pA + (bf ? hbA : 0);
    };

    if (ws_size >= need(4, true))
        run_all<4, 1>(features, initf, W, src, dst, out, d_ws, n, E, stream);
    else if (ws_size >= need(2, true))
        run_all<2, 1>(features, initf, W, src, dst, out, d_ws, n, E, stream);
    else if (ws_size >= need(1, true))
        run_all<1, 1>(features, initf, W, src, dst, out, d_ws, n, E, stream);
    else
        run_all<1, 0>(features, initf, W, src, dst, out, d_ws, n, E, stream);
}

// Round 7
// 238.875 us; speedup vs baseline: 1.7902x; 1.1968x over previous
//
#include <hip/hip_runtime.h>
#include <math.h>

#define D 128
#define THREADS 256

typedef __attribute__((ext_vector_type(8))) short s16x8;   // 8 bf16 (4 VGPR)
typedef __attribute__((ext_vector_type(4))) float f32x4;   // MFMA acc

__device__ __forceinline__ unsigned short f2bf(float f) {  // RNE float->bf16
    unsigned u = __float_as_uint(f);
    u += 0x7FFFu + ((u >> 16) & 1u);
    return (unsigned short)(u >> 16);
}
__device__ __forceinline__ float bflo(unsigned u) { return __uint_as_float(u << 16); }
__device__ __forceinline__ float bfhi(unsigned u) { return __uint_as_float(u & 0xFFFF0000u); }

// ---------------------------------------------------------------------------
// Phase 1: linked-list build, ONE atomic per edge. WAYS chains per node.
// p[e] = {next, src} packed -> one 64B line per hop.
// ---------------------------------------------------------------------------
template <int WAYS>
__global__ __launch_bounds__(THREADS) void k_build(
    const int* __restrict__ src, const int* __restrict__ dst,
    int* __restrict__ head, int2* __restrict__ p, int E) {
    int e = blockIdx.x * THREADS + threadIdx.x;
    if (e < E) {
        int d = dst[e];
        int nx = atomicExch(&head[(size_t)d * WAYS + (e & (WAYS - 1))], e);
        p[e] = make_int2(nx, src[e]);   // coalesced 8B store
    }
}

// ---------------------------------------------------------------------------
// Phase 2: deg by chain-length count + norm = rsqrt(max(deg,1)).
// ---------------------------------------------------------------------------
template <int WAYS>
__global__ __launch_bounds__(THREADS) void k_normwalk(
    const int* __restrict__ head, const int2* __restrict__ p,
    float* __restrict__ normf, int n) {
    int i = blockIdx.x * THREADS + threadIdx.x;
    if (i >= n) return;
    int c[WAYS];
#pragma unroll
    for (int w = 0; w < WAYS; ++w) c[w] = head[(size_t)i * WAYS + w];
    int cnt = 0;
    bool any = false;
#pragma unroll
    for (int w = 0; w < WAYS; ++w) any |= (c[w] >= 0);
    while (any) {
        any = false;
#pragma unroll
        for (int w = 0; w < WAYS; ++w) {
            if (c[w] >= 0) {
                ++cnt;
                c[w] = p[c[w]].x;
                any |= (c[w] >= 0);
            }
        }
    }
    normf[i] = rsqrtf(fmaxf((float)cnt, 1.0f));
}

// ---------------------------------------------------------------------------
// Phase 3: hb[i][k] = bf16(features[i][k] * norm[i])
// ---------------------------------------------------------------------------
__global__ __launch_bounds__(THREADS) void k_scale(
    const float* __restrict__ f, const float* __restrict__ nrm,
    uint4* __restrict__ hb, int n) {
    int c = blockIdx.x * THREADS + threadIdx.x;  // one 8-float chunk
    if (c >= n * 16) return;
    float nv = nrm[c >> 4];
    const float4* fp = (const float4*)f;
    float4 a = fp[c * 2], b = fp[c * 2 + 1];
    uint4 o;
    o.x = f2bf(a.x * nv) | ((unsigned)f2bf(a.y * nv) << 16);
    o.y = f2bf(a.z * nv) | ((unsigned)f2bf(a.w * nv) << 16);
    o.z = f2bf(b.x * nv) | ((unsigned)f2bf(b.y * nv) << 16);
    o.w = f2bf(b.z * nv) | ((unsigned)f2bf(b.w * nv) << 16);
    hb[c] = o;
}

// ---------------------------------------------------------------------------
// Phase 4: standalone gather — NO LDS, NO barriers, high occupancy.
// One 16-lane group per node walks WAYS chains interleaved; writes
// t = 0.9*norm*agg + 0.1*init as fp32 rows into `out` (in-place staging,
// consumed by k_gemm which reads exactly the rows it overwrites).
// ---------------------------------------------------------------------------
template <int WAYS, int BF>
__global__ __launch_bounds__(THREADS) void k_gather(
    const uint4* __restrict__ hb, const float* __restrict__ features,
    const float* __restrict__ initf, const int* __restrict__ head,
    const int2* __restrict__ p, const float* __restrict__ normf,
    float* __restrict__ out, int n) {
    const int g = (blockIdx.x * THREADS + threadIdx.x) >> 4;   // node
    if (g >= n) return;
    const int gl = threadIdx.x & 15;

    float acc[8] = {0.f, 0.f, 0.f, 0.f, 0.f, 0.f, 0.f, 0.f};
    int c[WAYS];
#pragma unroll
    for (int w = 0; w < WAYS; ++w) c[w] = head[(size_t)g * WAYS + w];
    bool any = false;
#pragma unroll
    for (int w = 0; w < WAYS; ++w) any |= (c[w] >= 0);
    while (any) {
        int2 pc[WAYS];
#pragma unroll
        for (int w = 0; w < WAYS; ++w)    // issue all p-loads first
            if (c[w] >= 0) pc[w] = p[c[w]];
        any = false;
#pragma unroll
        for (int w = 0; w < WAYS; ++w) {
            if (c[w] >= 0) {
                if (BF) {
                    const uint4 r = hb[(size_t)pc[w].y * 16 + gl];   // 256B row
                    acc[0] += bflo(r.x); acc[1] += bfhi(r.x);
                    acc[2] += bflo(r.y); acc[3] += bfhi(r.y);
                    acc[4] += bflo(r.z); acc[5] += bfhi(r.z);
                    acc[6] += bflo(r.w); acc[7] += bfhi(r.w);
                } else {
                    const float ww = normf[pc[w].y];
                    const float4* fr = (const float4*)(features + (size_t)pc[w].y * D);
                    const float4 f0 = fr[gl * 2], f1 = fr[gl * 2 + 1];
                    acc[0] += f0.x * ww; acc[1] += f0.y * ww;
                    acc[2] += f0.z * ww; acc[3] += f0.w * ww;
                    acc[4] += f1.x * ww; acc[5] += f1.y * ww;
                    acc[6] += f1.z * ww; acc[7] += f1.w * ww;
                }
                c[w] = pc[w].x;
                any |= (c[w] >= 0);
            }
        }
    }

    const float nv = 0.9f * normf[g];
    const float4* iv = (const float4*)(initf + (size_t)g * D);
    const float4 i0 = iv[gl * 2], i1 = iv[gl * 2 + 1];
    float4 t0, t1;
    t0.x = nv * acc[0] + 0.1f * i0.x; t0.y = nv * acc[1] + 0.1f * i0.y;
    t0.z = nv * acc[2] + 0.1f * i0.z; t0.w = nv * acc[3] + 0.1f * i0.w;
    t1.x = nv * acc[4] + 0.1f * i1.x; t1.y = nv * acc[5] + 0.1f * i1.y;
    t1.z = nv * acc[6] + 0.1f * i1.z; t1.w = nv * acc[7] + 0.1f * i1.w;
    float4* orow = (float4*)(out + (size_t)g * D);
    orow[gl * 2] = t0;          // 16 lanes x 32B = 512B coalesced row
    orow[gl * 2 + 1] = t1;
}

// ---------------------------------------------------------------------------
// Phase 5: out = relu(t @ M^T) in place, M = 0.5*W + 0.5*I (bf16 MFMA).
// Per 32-node tile: read own rows -> sT (swizzled bf16), barrier, MFMA vs
// sMt, relu, overwrite. Deterministic per-tile cost; barriers cheap now.
// ---------------------------------------------------------------------------
__global__ __launch_bounds__(THREADS) void k_gemm(
    const float* __restrict__ W, float* __restrict__ out, int n, int numTiles) {

    __shared__ uint4 sMt[D * 16];   // 32 KB: M[j][k] bf16, swizzled
    __shared__ uint4 sT[32 * 16];   // 8 KB: t[node][k] bf16, swizzled

    const int tid = threadIdx.x;

    // ---- stage M once per block: D rows x 16 chunks of 8 bf16 ----
    for (int c = tid; c < D * 16; c += THREADS) {
        const int j = c >> 4, kc = c & 15;
        const float* wr = W + j * D + kc * 8;
        float m[8];
#pragma unroll
        for (int q = 0; q < 8; ++q) m[q] = 0.5f * wr[q];
        const int dj = j - kc * 8;
        if (dj >= 0 && dj < 8) m[dj] += 0.5f;   // + 0.5*I
        uint4 o;
        o.x = f2bf(m[0]) | ((unsigned)f2bf(m[1]) << 16);
        o.y = f2bf(m[2]) | ((unsigned)f2bf(m[3]) << 16);
        o.z = f2bf(m[4]) | ((unsigned)f2bf(m[5]) << 16);
        o.w = f2bf(m[6]) | ((unsigned)f2bf(m[7]) << 16);
        sMt[j * 16 + (kc ^ (j & 7))] = o;
    }
    __syncthreads();

    const int sn = tid >> 3;            // staging: node 0..31
    const int c0 = (tid & 7) * 2;       // staging: 2 chunks of 8 floats
    const int wave = tid >> 6, lane = tid & 63;
    const int l15 = lane & 15, lq = lane >> 4;
    const int mt = wave & 1, ntb = (wave >> 1) * 4;

    for (int tile = blockIdx.x; tile < numTiles; tile += gridDim.x) {
        const int base = tile << 5;

        // ---- stage t rows (fp32 in `out`) -> bf16 swizzled sT ----
        {
            const int node = base + sn;
#pragma unroll
            for (int s = 0; s < 2; ++s) {
                const int cc = c0 + s;
                uint4 o;
                if (node < n) {
                    const float4* tr = (const float4*)(out + (size_t)node * D);
                    const float4 a = tr[cc * 2], b = tr[cc * 2 + 1];
                    o.x = f2bf(a.x) | ((unsigned)f2bf(a.y) << 16);
                    o.y = f2bf(a.z) | ((unsigned)f2bf(a.w) << 16);
                    o.z = f2bf(b.x) | ((unsigned)f2bf(b.y) << 16);
                    o.w = f2bf(b.z) | ((unsigned)f2bf(b.w) << 16);
                } else {
                    o.x = o.y = o.z = o.w = 0u;
                }
                sT[sn * 16 + (cc ^ (sn & 7))] = o;
            }
        }
        __syncthreads();

        // ---- GEMM: out[tile] = relu(T @ M^T), 16 MFMA per wave ----
        const int nr = mt * 16 + l15;
        s16x8 a[4];
#pragma unroll
        for (int ks = 0; ks < 4; ++ks)
            a[ks] = *reinterpret_cast<const s16x8*>(
                &sT[nr * 16 + ((ks * 4 + lq) ^ (nr & 7))]);

#pragma unroll
        for (int tnt = 0; tnt < 4; ++tnt) {
            const int nt = ntb + tnt;
            const int jr = nt * 16 + l15;
            f32x4 c = {0.f, 0.f, 0.f, 0.f};
#pragma unroll
            for (int ks = 0; ks < 4; ++ks) {
                const s16x8 b = *reinterpret_cast<const s16x8*>(
                    &sMt[jr * 16 + ((ks * 4 + lq) ^ (jr & 7))]);
                c = __builtin_amdgcn_mfma_f32_16x16x32_bf16(a[ks], b, c, 0, 0, 0);
            }
            const int col = nt * 16 + l15;
            const int row0 = base + mt * 16 + lq * 4;
#pragma unroll
            for (int r = 0; r < 4; ++r) {
                const int node = row0 + r;
                if (node < n) out[(size_t)node * D + col] = fmaxf(c[r], 0.f);
            }
        }
        __syncthreads();   // sT reused next tile
    }
}

// ---------------------------------------------------------------------------
template <int WAYS, int BF>
static void run_all(const float* features, const float* initf, const float* W,
                    const int* src, const int* dst, float* out, void* d_ws,
                    int n, int E, hipStream_t stream) {
    const size_t nA = ((size_t)n * 4 + 15) & ~(size_t)15;
    const size_t pA = ((size_t)E * 8 + 15) & ~(size_t)15;
    float* normf = (float*)d_ws;
    int*   head  = (int*)((char*)d_ws + nA);
    int2*  p     = (int2*)((char*)d_ws + nA + (size_t)WAYS * nA);
    uint4* hb    = (uint4*)((char*)d_ws + nA + (size_t)WAYS * nA + pA);

    hipMemsetAsync(head, 0xFF, (size_t)WAYS * n * 4, stream);  // head = -1

    k_build<WAYS><<<(E + THREADS - 1) / THREADS, THREADS, 0, stream>>>(
        src, dst, head, p, E);
    k_normwalk<WAYS><<<(n + THREADS - 1) / THREADS, THREADS, 0, stream>>>(
        head, p, normf, n);
    if (BF)
        k_scale<<<(n * 16 + THREADS - 1) / THREADS, THREADS, 0, stream>>>(
            features, normf, hb, n);

    k_gather<WAYS, BF><<<((size_t)n * 16 + THREADS - 1) / THREADS, THREADS, 0, stream>>>(
        hb, features, initf, head, p, normf, out, n);

    const int numTiles = (n + 31) >> 5;
    const int grid = numTiles < 1024 ? numTiles : 1024;  // 4 blocks/CU (40KB LDS)
    k_gemm<<<grid, THREADS, 0, stream>>>(W, out, n, numTiles);
}

extern "C" void kernel_launch(void* const* d_in, const int* in_sizes, int n_in,
                              void* d_out, int out_size, void* d_ws, size_t ws_size,
                              hipStream_t stream) {
    const float* features = (const float*)d_in[0];
    const float* initf    = (const float*)d_in[1];
    const float* W        = (const float*)d_in[2];
    const int*   src      = (const int*)d_in[3];
    const int*   dst      = (const int*)d_in[4];
    float* out = (float*)d_out;

    const int n = in_sizes[0] / D;
    const int E = in_sizes[3];
    if (n <= 0) return;

    const size_t nA = ((size_t)n * 4 + 15) & ~(size_t)15;
    const size_t pA = ((size_t)E * 8 + 15) & ~(size_t)15;
    const size_t hbA = (size_t)n * 256;
    auto need = [&](int ways, bool bf) {
        return nA + (size_t)ways * nA + pA + (bf ? hbA : 0);
    };

    if (ws_size >= need(4, true))
        run_all<4, 1>(features, initf, W, src, dst, out, d_ws, n, E, stream);
    else if (ws_size >= need(2, true))
        run_all<2, 1>(features, initf, W, src, dst, out, d_ws, n, E, stream);
    else if (ws_size >= need(1, true))
        run_all<1, 1>(features, initf, W, src, dst, out, d_ws, n, E, stream);
    else
        run_all<1, 0>(features, initf, W, src, dst, out, d_ws, n, E, stream);
}

// Round 8
// 223.573 us; speedup vs baseline: 1.9127x; 1.0684x over previous
//
#include <hip/hip_runtime.h>
#include <math.h>

#define D 128
#define THREADS 256
#define PAD 32   // padded adjacency width; deg>PAD falls back to chain walk

typedef __attribute__((ext_vector_type(8))) short s16x8;   // 8 bf16 (4 VGPR)
typedef __attribute__((ext_vector_type(4))) float f32x4;   // MFMA acc

__device__ __forceinline__ unsigned short f2bf(float f) {  // RNE float->bf16
    unsigned u = __float_as_uint(f);
    u += 0x7FFFu + ((u >> 16) & 1u);
    return (unsigned short)(u >> 16);
}
__device__ __forceinline__ float bflo(unsigned u) { return __uint_as_float(u << 16); }
__device__ __forceinline__ float bfhi(unsigned u) { return __uint_as_float(u & 0xFFFF0000u); }

// ---------------------------------------------------------------------------
// Phase 1: linked-list build, ONE atomic per edge. WAYS chains per node.
// ---------------------------------------------------------------------------
template <int WAYS>
__global__ __launch_bounds__(THREADS) void k_build(
    const int* __restrict__ src, const int* __restrict__ dst,
    int* __restrict__ head, int2* __restrict__ p, int E) {
    int e = blockIdx.x * THREADS + threadIdx.x;
    if (e < E) {
        int d = dst[e];
        int nx = atomicExch(&head[(size_t)d * WAYS + (e & (WAYS - 1))], e);
        p[e] = make_int2(nx, src[e]);   // coalesced 8B store
    }
}

// ---------------------------------------------------------------------------
// Phase 2 (tier A/B): walk chains ONCE -> padded adjacency + deg + norm.
// Removes the pointer chase from k_gather entirely. deg>PAD nodes keep the
// (still valid) chain as fallback.
// ---------------------------------------------------------------------------
template <int WAYS>
__global__ __launch_bounds__(THREADS) void k_compact(
    const int* __restrict__ head, const int2* __restrict__ p,
    int* __restrict__ pad, int* __restrict__ degA,
    float* __restrict__ normf, int n) {
    int i = blockIdx.x * THREADS + threadIdx.x;
    if (i >= n) return;
    int c[WAYS];
#pragma unroll
    for (int w = 0; w < WAYS; ++w) c[w] = head[(size_t)i * WAYS + w];
    int cnt = 0;
    bool any = false;
#pragma unroll
    for (int w = 0; w < WAYS; ++w) any |= (c[w] >= 0);
    while (any) {
        any = false;
#pragma unroll
        for (int w = 0; w < WAYS; ++w) {
            if (c[w] >= 0) {
                const int2 pc = p[c[w]];
                if (cnt < PAD) pad[(size_t)i * PAD + cnt] = pc.y;
                ++cnt;
                c[w] = pc.x;
                any |= (c[w] >= 0);
            }
        }
    }
    degA[i] = cnt;
    normf[i] = rsqrtf(fmaxf((float)cnt, 1.0f));
}

// ---------------------------------------------------------------------------
// Phase 2 (tier C fallback): deg by chain count + norm only.
// ---------------------------------------------------------------------------
template <int WAYS>
__global__ __launch_bounds__(THREADS) void k_normwalk(
    const int* __restrict__ head, const int2* __restrict__ p,
    float* __restrict__ normf, int n) {
    int i = blockIdx.x * THREADS + threadIdx.x;
    if (i >= n) return;
    int c[WAYS];
#pragma unroll
    for (int w = 0; w < WAYS; ++w) c[w] = head[(size_t)i * WAYS + w];
    int cnt = 0;
    bool any = false;
#pragma unroll
    for (int w = 0; w < WAYS; ++w) any |= (c[w] >= 0);
    while (any) {
        any = false;
#pragma unroll
        for (int w = 0; w < WAYS; ++w) {
            if (c[w] >= 0) { ++cnt; c[w] = p[c[w]].x; any |= (c[w] >= 0); }
        }
    }
    normf[i] = rsqrtf(fmaxf((float)cnt, 1.0f));
}

// ---------------------------------------------------------------------------
// Phase 3: hb[i][k] = bf16(features[i][k] * norm[i])
// ---------------------------------------------------------------------------
__global__ __launch_bounds__(THREADS) void k_scale(
    const float* __restrict__ f, const float* __restrict__ nrm,
    uint4* __restrict__ hb, int n) {
    int c = blockIdx.x * THREADS + threadIdx.x;  // one 8-float chunk
    if (c >= n * 16) return;
    float nv = nrm[c >> 4];
    const float4* fp = (const float4*)f;
    float4 a = fp[c * 2], b = fp[c * 2 + 1];
    uint4 o;
    o.x = f2bf(a.x * nv) | ((unsigned)f2bf(a.y * nv) << 16);
    o.y = f2bf(a.z * nv) | ((unsigned)f2bf(a.w * nv) << 16);
    o.z = f2bf(b.x * nv) | ((unsigned)f2bf(b.y * nv) << 16);
    o.w = f2bf(b.z * nv) | ((unsigned)f2bf(b.w * nv) << 16);
    hb[c] = o;
}

// ---------------------------------------------------------------------------
// Phase 4 (tier A/B): gather over PADDED adjacency — no dependent loads.
// 16 lanes/node, 16B/lane. int4 index loads keep 4 row-gathers in flight.
// TB=1: write t as packed bf16 (k_gemm converts anyway -> no extra error).
// TB=0: write t fp32 into `out` (in-place staging).
// ---------------------------------------------------------------------------
template <int WAYS, int TB>
__global__ __launch_bounds__(THREADS) void k_gather_pad(
    const uint4* __restrict__ hb, const float* __restrict__ initf,
    const int* __restrict__ pad, const int* __restrict__ degA,
    const int* __restrict__ head, const int2* __restrict__ p,
    const float* __restrict__ normf, uint4* __restrict__ tb,
    float* __restrict__ outT, int n) {
    const int g = (blockIdx.x * THREADS + threadIdx.x) >> 4;   // node
    if (g >= n) return;
    const int gl = threadIdx.x & 15;

    float acc[8] = {0.f, 0.f, 0.f, 0.f, 0.f, 0.f, 0.f, 0.f};

#define ROW(S)                                                      \
    {                                                               \
        const uint4 r = hb[(size_t)(S)*16 + gl];                    \
        acc[0] += bflo(r.x); acc[1] += bfhi(r.x);                   \
        acc[2] += bflo(r.y); acc[3] += bfhi(r.y);                   \
        acc[4] += bflo(r.z); acc[5] += bfhi(r.z);                   \
        acc[6] += bflo(r.w); acc[7] += bfhi(r.w);                   \
    }

    const int deg = degA[g];
    if (deg <= PAD) {
        const int* pl = pad + (size_t)g * PAD;
        int j = 0;
        for (; j + 4 <= deg; j += 4) {
            const int4 s4 = *reinterpret_cast<const int4*>(pl + j);
            ROW(s4.x); ROW(s4.y); ROW(s4.z); ROW(s4.w);
        }
        for (; j < deg; ++j) ROW(pl[j]);
    } else {  // rare overflow: chain walk (head/p still valid)
        int c[WAYS];
#pragma unroll
        for (int w = 0; w < WAYS; ++w) c[w] = head[(size_t)g * WAYS + w];
        bool any = false;
#pragma unroll
        for (int w = 0; w < WAYS; ++w) any |= (c[w] >= 0);
        while (any) {
            int2 pc[WAYS];
#pragma unroll
            for (int w = 0; w < WAYS; ++w)
                if (c[w] >= 0) pc[w] = p[c[w]];
            any = false;
#pragma unroll
            for (int w = 0; w < WAYS; ++w) {
                if (c[w] >= 0) {
                    ROW(pc[w].y);
                    c[w] = pc[w].x;
                    any |= (c[w] >= 0);
                }
            }
        }
    }
#undef ROW

    const float nv = 0.9f * normf[g];
    const float4* iv = (const float4*)(initf + (size_t)g * D);
    const float4 i0 = iv[gl * 2], i1 = iv[gl * 2 + 1];
    float t[8];
    t[0] = nv * acc[0] + 0.1f * i0.x; t[1] = nv * acc[1] + 0.1f * i0.y;
    t[2] = nv * acc[2] + 0.1f * i0.z; t[3] = nv * acc[3] + 0.1f * i0.w;
    t[4] = nv * acc[4] + 0.1f * i1.x; t[5] = nv * acc[5] + 0.1f * i1.y;
    t[6] = nv * acc[6] + 0.1f * i1.z; t[7] = nv * acc[7] + 0.1f * i1.w;

    if (TB) {
        uint4 o;
        o.x = f2bf(t[0]) | ((unsigned)f2bf(t[1]) << 16);
        o.y = f2bf(t[2]) | ((unsigned)f2bf(t[3]) << 16);
        o.z = f2bf(t[4]) | ((unsigned)f2bf(t[5]) << 16);
        o.w = f2bf(t[6]) | ((unsigned)f2bf(t[7]) << 16);
        tb[(size_t)g * 16 + gl] = o;
    } else {
        float4* orow = (float4*)(outT + (size_t)g * D);
        float4 t0 = {t[0], t[1], t[2], t[3]};
        float4 t1 = {t[4], t[5], t[6], t[7]};
        orow[gl * 2] = t0;
        orow[gl * 2 + 1] = t1;
    }
}

// ---------------------------------------------------------------------------
// Phase 4 (tier C): round-7 chain gather, fp32 t into `out`.
// ---------------------------------------------------------------------------
template <int WAYS, int BF>
__global__ __launch_bounds__(THREADS) void k_gather(
    const uint4* __restrict__ hb, const float* __restrict__ features,
    const float* __restrict__ initf, const int* __restrict__ head,
    const int2* __restrict__ p, const float* __restrict__ normf,
    float* __restrict__ out, int n) {
    const int g = (blockIdx.x * THREADS + threadIdx.x) >> 4;
    if (g >= n) return;
    const int gl = threadIdx.x & 15;

    float acc[8] = {0.f, 0.f, 0.f, 0.f, 0.f, 0.f, 0.f, 0.f};
    int c[WAYS];
#pragma unroll
    for (int w = 0; w < WAYS; ++w) c[w] = head[(size_t)g * WAYS + w];
    bool any = false;
#pragma unroll
    for (int w = 0; w < WAYS; ++w) any |= (c[w] >= 0);
    while (any) {
        int2 pc[WAYS];
#pragma unroll
        for (int w = 0; w < WAYS; ++w)
            if (c[w] >= 0) pc[w] = p[c[w]];
        any = false;
#pragma unroll
        for (int w = 0; w < WAYS; ++w) {
            if (c[w] >= 0) {
                if (BF) {
                    const uint4 r = hb[(size_t)pc[w].y * 16 + gl];
                    acc[0] += bflo(r.x); acc[1] += bfhi(r.x);
                    acc[2] += bflo(r.y); acc[3] += bfhi(r.y);
                    acc[4] += bflo(r.z); acc[5] += bfhi(r.z);
                    acc[6] += bflo(r.w); acc[7] += bfhi(r.w);
                } else {
                    const float ww = normf[pc[w].y];
                    const float4* fr = (const float4*)(features + (size_t)pc[w].y * D);
                    const float4 f0 = fr[gl * 2], f1 = fr[gl * 2 + 1];
                    acc[0] += f0.x * ww; acc[1] += f0.y * ww;
                    acc[2] += f0.z * ww; acc[3] += f0.w * ww;
                    acc[4] += f1.x * ww; acc[5] += f1.y * ww;
                    acc[6] += f1.z * ww; acc[7] += f1.w * ww;
                }
                c[w] = pc[w].x;
                any |= (c[w] >= 0);
            }
        }
    }

    const float nv = 0.9f * normf[g];
    const float4* iv = (const float4*)(initf + (size_t)g * D);
    const float4 i0 = iv[gl * 2], i1 = iv[gl * 2 + 1];
    float4 t0, t1;
    t0.x = nv * acc[0] + 0.1f * i0.x; t0.y = nv * acc[1] + 0.1f * i0.y;
    t0.z = nv * acc[2] + 0.1f * i0.z; t0.w = nv * acc[3] + 0.1f * i0.w;
    t1.x = nv * acc[4] + 0.1f * i1.x; t1.y = nv * acc[5] + 0.1f * i1.y;
    t1.z = nv * acc[6] + 0.1f * i1.z; t1.w = nv * acc[7] + 0.1f * i1.w;
    float4* orow = (float4*)(out + (size_t)g * D);
    orow[gl * 2] = t0;
    orow[gl * 2 + 1] = t1;
}

// ---------------------------------------------------------------------------
// Shared M staging for the GEMM kernels.
// ---------------------------------------------------------------------------
__device__ __forceinline__ void stage_M(const float* __restrict__ W,
                                        uint4* __restrict__ sMt, int tid) {
    for (int c = tid; c < D * 16; c += THREADS) {
        const int j = c >> 4, kc = c & 15;
        const float* wr = W + j * D + kc * 8;
        float m[8];
#pragma unroll
        for (int q = 0; q < 8; ++q) m[q] = 0.5f * wr[q];
        const int dj = j - kc * 8;
        if (dj >= 0 && dj < 8) m[dj] += 0.5f;   // + 0.5*I
        uint4 o;
        o.x = f2bf(m[0]) | ((unsigned)f2bf(m[1]) << 16);
        o.y = f2bf(m[2]) | ((unsigned)f2bf(m[3]) << 16);
        o.z = f2bf(m[4]) | ((unsigned)f2bf(m[5]) << 16);
        o.w = f2bf(m[6]) | ((unsigned)f2bf(m[7]) << 16);
        sMt[j * 16 + (kc ^ (j & 7))] = o;
    }
}

__device__ __forceinline__ void gemm_tile(const uint4* __restrict__ sMt,
                                          const uint4* __restrict__ sT,
                                          float* __restrict__ out,
                                          int base, int n, int lane, int wave) {
    const int l15 = lane & 15, lq = lane >> 4;
    const int mt = wave & 1, ntb = (wave >> 1) * 4;
    const int nr = mt * 16 + l15;
    s16x8 a[4];
#pragma unroll
    for (int ks = 0; ks < 4; ++ks)
        a[ks] = *reinterpret_cast<const s16x8*>(
            &sT[nr * 16 + ((ks * 4 + lq) ^ (nr & 7))]);

#pragma unroll
    for (int tnt = 0; tnt < 4; ++tnt) {
        const int nt = ntb + tnt;
        const int jr = nt * 16 + l15;
        f32x4 c = {0.f, 0.f, 0.f, 0.f};
#pragma unroll
        for (int ks = 0; ks < 4; ++ks) {
            const s16x8 b = *reinterpret_cast<const s16x8*>(
                &sMt[jr * 16 + ((ks * 4 + lq) ^ (jr & 7))]);
            c = __builtin_amdgcn_mfma_f32_16x16x32_bf16(a[ks], b, c, 0, 0, 0);
        }
        const int col = nt * 16 + l15;
        const int row0 = base + mt * 16 + lq * 4;
#pragma unroll
        for (int r = 0; r < 4; ++r) {
            const int node = row0 + r;
            if (node < n) out[(size_t)node * D + col] = fmaxf(c[r], 0.f);
        }
    }
}

// ---------------------------------------------------------------------------
// Phase 5a (tier A): out = relu(t @ M^T), t read from bf16 tb (no convert).
// ---------------------------------------------------------------------------
__global__ __launch_bounds__(THREADS) void k_gemm_tb(
    const float* __restrict__ W, const uint4* __restrict__ tb,
    float* __restrict__ out, int n, int numTiles) {
    __shared__ uint4 sMt[D * 16];   // 32 KB
    __shared__ uint4 sT[32 * 16];   // 8 KB
    const int tid = threadIdx.x;
    stage_M(W, sMt, tid);
    __syncthreads();

    const int sn = tid >> 3;
    const int c0 = (tid & 7) * 2;
    const int wave = tid >> 6, lane = tid & 63;

    for (int tile = blockIdx.x; tile < numTiles; tile += gridDim.x) {
        const int base = tile << 5;
        {
            const int node = base + sn;
#pragma unroll
            for (int s = 0; s < 2; ++s) {
                const int cc = c0 + s;
                uint4 o;
                if (node < n) o = tb[(size_t)node * 16 + cc];
                else o.x = o.y = o.z = o.w = 0u;
                sT[sn * 16 + (cc ^ (sn & 7))] = o;
            }
        }
        __syncthreads();
        gemm_tile(sMt, sT, out, base, n, lane, wave);
        __syncthreads();
    }
}

// ---------------------------------------------------------------------------
// Phase 5b (tier B/C): out = relu(t @ M^T) in place, t fp32 in `out`.
// ---------------------------------------------------------------------------
__global__ __launch_bounds__(THREADS) void k_gemm(
    const float* __restrict__ W, float* __restrict__ out, int n, int numTiles) {
    __shared__ uint4 sMt[D * 16];
    __shared__ uint4 sT[32 * 16];
    const int tid = threadIdx.x;
    stage_M(W, sMt, tid);
    __syncthreads();

    const int sn = tid >> 3;
    const int c0 = (tid & 7) * 2;
    const int wave = tid >> 6, lane = tid & 63;

    for (int tile = blockIdx.x; tile < numTiles; tile += gridDim.x) {
        const int base = tile << 5;
        {
            const int node = base + sn;
#pragma unroll
            for (int s = 0; s < 2; ++s) {
                const int cc = c0 + s;
                uint4 o;
                if (node < n) {
                    const float4* tr = (const float4*)(out + (size_t)node * D);
                    const float4 a = tr[cc * 2], b = tr[cc * 2 + 1];
                    o.x = f2bf(a.x) | ((unsigned)f2bf(a.y) << 16);
                    o.y = f2bf(a.z) | ((unsigned)f2bf(a.w) << 16);
                    o.z = f2bf(b.x) | ((unsigned)f2bf(b.y) << 16);
                    o.w = f2bf(b.z) | ((unsigned)f2bf(b.w) << 16);
                } else {
                    o.x = o.y = o.z = o.w = 0u;
                }
                sT[sn * 16 + (cc ^ (sn & 7))] = o;
            }
        }
        __syncthreads();
        gemm_tile(sMt, sT, out, base, n, lane, wave);
        __syncthreads();
    }
}

// ---------------------------------------------------------------------------
extern "C" void kernel_launch(void* const* d_in, const int* in_sizes, int n_in,
                              void* d_out, int out_size, void* d_ws, size_t ws_size,
                              hipStream_t stream) {
    const float* features = (const float*)d_in[0];
    const float* initf    = (const float*)d_in[1];
    const float* W        = (const float*)d_in[2];
    const int*   src      = (const int*)d_in[3];
    const int*   dst      = (const int*)d_in[4];
    float* out = (float*)d_out;

    const int n = in_sizes[0] / D;
    const int E = in_sizes[3];
    if (n <= 0) return;

    const size_t nA  = ((size_t)n * 4 + 15) & ~(size_t)15;
    const size_t pA  = ((size_t)E * 8 + 15) & ~(size_t)15;
    const size_t hbA = (size_t)n * 256;           // bf16 rows
    const size_t padA = (size_t)n * PAD * 4;      // padded adjacency
    const size_t tbA = (size_t)n * 256;           // bf16 t rows

    const int WAYS = 4;
    char* base = (char*)d_ws;
    float* normf = (float*)base;
    int*   degA  = (int*)(base + nA);
    int*   head  = (int*)(base + 2 * nA);
    int2*  p     = (int2*)(base + 2 * nA + WAYS * nA);
    uint4* hb    = (uint4*)(base + 2 * nA + WAYS * nA + pA);
    int*   pad   = (int*)(base + 2 * nA + WAYS * nA + pA + hbA);
    uint4* tb    = (uint4*)(base + 2 * nA + WAYS * nA + pA + hbA + padA);

    const size_t needC = 2 * nA + WAYS * nA + pA + hbA;          // ~40.8 MB
    const size_t needB = needC + padA;                            // ~53.6 MB
    const size_t needA = needB + tbA;                             // ~79.2 MB

    const int gridE = (E + THREADS - 1) / THREADS;
    const int gridN = (n + THREADS - 1) / THREADS;
    const int gridG = (int)(((size_t)n * 16 + THREADS - 1) / THREADS);
    const int numTiles = (n + 31) >> 5;
    const int gridT = numTiles < 1024 ? numTiles : 1024;  // 40KB LDS -> 4/CU

    hipMemsetAsync(head, 0xFF, (size_t)WAYS * n * 4, stream);  // head = -1
    k_build<WAYS><<<gridE, THREADS, 0, stream>>>(src, dst, head, p, E);

    if (ws_size >= needA) {
        k_compact<WAYS><<<gridN, THREADS, 0, stream>>>(head, p, pad, degA, normf, n);
        k_scale<<<(n * 16 + THREADS - 1) / THREADS, THREADS, 0, stream>>>(
            features, normf, hb, n);
        k_gather_pad<WAYS, 1><<<gridG, THREADS, 0, stream>>>(
            hb, initf, pad, degA, head, p, normf, tb, out, n);
        k_gemm_tb<<<gridT, THREADS, 0, stream>>>(W, tb, out, n, numTiles);
    } else if (ws_size >= needB) {
        k_compact<WAYS><<<gridN, THREADS, 0, stream>>>(head, p, pad, degA, normf, n);
        k_scale<<<(n * 16 + THREADS - 1) / THREADS, THREADS, 0, stream>>>(
            features, normf, hb, n);
        k_gather_pad<WAYS, 0><<<gridG, THREADS, 0, stream>>>(
            hb, initf, pad, degA, head, p, normf, (uint4*)out, out, n);
        k_gemm<<<gridT, THREADS, 0, stream>>>(W, out, n, numTiles);
    } else if (ws_size >= needC) {
        k_normwalk<WAYS><<<gridN, THREADS, 0, stream>>>(head, p, normf, n);
        k_scale<<<(n * 16 + THREADS - 1) / THREADS, THREADS, 0, stream>>>(
            features, normf, hb, n);
        k_gather<WAYS, 1><<<gridG, THREADS, 0, stream>>>(
            hb, features, initf, head, p, normf, out, n);
        k_gemm<<<gridT, THREADS, 0, stream>>>(W, out, n, numTiles);
    } else {
        k_normwalk<WAYS><<<gridN, THREADS, 0, stream>>>(head, p, normf, n);
        k_gather<WAYS, 0><<<gridG, THREADS, 0, stream>>>(
            hb, features, initf, head, p, normf, out, n);
        k_gemm<<<gridT, THREADS, 0, stream>>>(W, out, n, numTiles);
    }
}

// Round 9
// 179.929 us; speedup vs baseline: 2.3766x; 1.2426x over previous
//
#include <hip/hip_runtime.h>
#include <math.h>

#define D 128
#define THREADS 256
#define BS 512           // nodes per bucket (bucket id = dst >> 9)
#define MAXB 1024        // max buckets handled by single-block scan (n <= 524288)
#define BIN_T 512        // threads in k_bin
#define BIN_CHUNK 4096   // edges per k_bin block (BIN_T * 8)

typedef __attribute__((ext_vector_type(8))) short s16x8;   // 8 bf16 (4 VGPR)
typedef __attribute__((ext_vector_type(4))) float f32x4;   // MFMA acc

__device__ __forceinline__ unsigned short f2bf(float f) {  // RNE float->bf16
    unsigned u = __float_as_uint(f);
    u += 0x7FFFu + ((u >> 16) & 1u);
    return (unsigned short)(u >> 16);
}
__device__ __forceinline__ float bflo(unsigned u) { return __uint_as_float(u << 16); }
__device__ __forceinline__ float bfhi(unsigned u) { return __uint_as_float(u & 0xFFFF0000u); }

// ===========================================================================
// Bucketed counting-sort preprocessing (replaces atomicExch chains + walk).
// ===========================================================================

// (A) global bucket histogram via per-block LDS histograms
__global__ __launch_bounds__(THREADS) void k_hist(const int* __restrict__ dst,
                                                  int* __restrict__ bcnt,
                                                  int E, int nbuck) {
    __shared__ int lh[MAXB];
    for (int b = threadIdx.x; b < nbuck; b += THREADS) lh[b] = 0;
    __syncthreads();
    const int stride = gridDim.x * THREADS;
    for (int e = blockIdx.x * THREADS + threadIdx.x; e < E; e += stride)
        atomicAdd(&lh[dst[e] >> 9], 1);
    __syncthreads();
    for (int b = threadIdx.x; b < nbuck; b += THREADS) {
        const int v = lh[b];
        if (v) atomicAdd(&bcnt[b], v);
    }
}

// (B) exclusive scan of bucket counts (single block)
__global__ __launch_bounds__(MAXB) void k_scan(const int* __restrict__ bcnt,
                                               int* __restrict__ bbase,
                                               int* __restrict__ bcur, int nbuck) {
    __shared__ int sh[MAXB];
    const int tid = threadIdx.x;
    const int v = (tid < nbuck) ? bcnt[tid] : 0;
    sh[tid] = v;
    __syncthreads();
    for (int s = 1; s < MAXB; s <<= 1) {
        const int t = (tid >= s) ? sh[tid - s] : 0;
        __syncthreads();
        sh[tid] += t;
        __syncthreads();
    }
    if (tid < nbuck) {
        const int ex = sh[tid] - v;
        bbase[tid] = ex;
        bcur[tid] = ex;
    }
    if (tid == nbuck - 1) bbase[nbuck] = sh[tid];  // = E
}

// (C) scatter edges into bucket-contiguous ebuf; one global atomic per
// (block,bucket) reservation, LDS atomics for intra-block rank.
__global__ __launch_bounds__(BIN_T) void k_bin(const int* __restrict__ src,
                                               const int* __restrict__ dst,
                                               int* __restrict__ bcur,
                                               int2* __restrict__ ebuf,
                                               int E, int nbuck) {
    __shared__ int lh[MAXB];
    __shared__ int lbase[MAXB];
    const int tid = threadIdx.x;
    for (int b = tid; b < nbuck; b += BIN_T) lh[b] = 0;
    __syncthreads();
    const int base = blockIdx.x * BIN_CHUNK;
    int2 ed[8];
#pragma unroll
    for (int k = 0; k < 8; ++k) {
        const int e = base + k * BIN_T + tid;
        if (e < E) {
            ed[k] = make_int2(dst[e], src[e]);
            atomicAdd(&lh[ed[k].x >> 9], 1);
        } else {
            ed[k].x = -1;
        }
    }
    __syncthreads();
    for (int b = tid; b < nbuck; b += BIN_T) {
        const int v = lh[b];
        lbase[b] = v ? atomicAdd(&bcur[b], v) : 0;
        lh[b] = 0;  // reuse as intra-block cursor
    }
    __syncthreads();
#pragma unroll
    for (int k = 0; k < 8; ++k) {
        if (ed[k].x >= 0) {
            const int b = ed[k].x >> 9;
            const int pos = lbase[b] + atomicAdd(&lh[b], 1);
            ebuf[pos] = ed[k];
        }
    }
}

// (D) per-bucket counting sort -> exact CSR (csr, off) + norm. One block
// per bucket; all LDS atomics; csr writes land in an L2-resident 64KB window.
__global__ __launch_bounds__(BS) void k_csr(const int* __restrict__ bbase,
                                            const int2* __restrict__ ebuf,
                                            int* __restrict__ csr,
                                            int* __restrict__ off,
                                            float* __restrict__ normf,
                                            int n, int nbuck) {
    __shared__ int cnt[BS];
    __shared__ int ex[BS];
    const int b = blockIdx.x, tid = threadIdx.x;
    const int lo = bbase[b], hi = bbase[b + 1];
    cnt[tid] = 0;
    __syncthreads();
    for (int e = lo + tid; e < hi; e += BS)
        atomicAdd(&cnt[ebuf[e].x & (BS - 1)], 1);
    __syncthreads();
    const int deg = cnt[tid];
    ex[tid] = deg;
    __syncthreads();
    for (int s = 1; s < BS; s <<= 1) {
        const int t = (tid >= s) ? ex[tid - s] : 0;
        __syncthreads();
        ex[tid] += t;
        __syncthreads();
    }
    const int excl = ex[tid] - deg;
    const int node = b * BS + tid;
    if (node < n) {
        off[node] = lo + excl;
        normf[node] = rsqrtf(fmaxf((float)deg, 1.0f));
    }
    if (b == nbuck - 1 && tid == 0) off[n] = bbase[nbuck];
    cnt[tid] = excl;  // reuse as cursor
    __syncthreads();
    for (int e = lo + tid; e < hi; e += BS) {
        const int2 edge = ebuf[e];
        const int p = atomicAdd(&cnt[edge.x & (BS - 1)], 1);
        csr[lo + p] = edge.y;
    }
}

// ===========================================================================
// hb[i][k] = bf16(features[i][k] * norm[i]) — premultiplied bf16 rows
// ===========================================================================
__global__ __launch_bounds__(THREADS) void k_scale(
    const float* __restrict__ f, const float* __restrict__ nrm,
    uint4* __restrict__ hb, int n) {
    int c = blockIdx.x * THREADS + threadIdx.x;  // one 8-float chunk
    if (c >= n * 16) return;
    float nv = nrm[c >> 4];
    const float4* fp = (const float4*)f;
    float4 a = fp[c * 2], b = fp[c * 2 + 1];
    uint4 o;
    o.x = f2bf(a.x * nv) | ((unsigned)f2bf(a.y * nv) << 16);
    o.y = f2bf(a.z * nv) | ((unsigned)f2bf(a.w * nv) << 16);
    o.z = f2bf(b.x * nv) | ((unsigned)f2bf(b.y * nv) << 16);
    o.w = f2bf(b.z * nv) | ((unsigned)f2bf(b.w * nv) << 16);
    hb[c] = o;
}

// ===========================================================================
// Gather over exact CSR: no dependent loads, csr reads are sequential
// broadcast lines. 16 lanes/node, 16B/lane; t written as packed bf16.
// ===========================================================================
__global__ __launch_bounds__(THREADS) void k_gather_csr(
    const uint4* __restrict__ hb, const float* __restrict__ initf,
    const int* __restrict__ off, const int* __restrict__ csr,
    const float* __restrict__ normf, uint4* __restrict__ tb, int n) {
    const int g = (blockIdx.x * THREADS + threadIdx.x) >> 4;   // node
    if (g >= n) return;
    const int gl = threadIdx.x & 15;

    float acc[8] = {0.f, 0.f, 0.f, 0.f, 0.f, 0.f, 0.f, 0.f};

#define ROW(S)                                                      \
    {                                                               \
        const uint4 r = hb[(size_t)(S)*16 + gl];                    \
        acc[0] += bflo(r.x); acc[1] += bfhi(r.x);                   \
        acc[2] += bflo(r.y); acc[3] += bfhi(r.y);                   \
        acc[4] += bflo(r.z); acc[5] += bfhi(r.z);                   \
        acc[6] += bflo(r.w); acc[7] += bfhi(r.w);                   \
    }
    const int begin = off[g], end = off[g + 1];
    int j = begin;
    for (; j + 4 <= end; j += 4) {
        const int s0 = csr[j], s1 = csr[j + 1], s2 = csr[j + 2], s3 = csr[j + 3];
        ROW(s0); ROW(s1); ROW(s2); ROW(s3);
    }
    for (; j < end; ++j) ROW(csr[j]);
#undef ROW

    const float nv = 0.9f * normf[g];
    const float4* iv = (const float4*)(initf + (size_t)g * D);
    const float4 i0 = iv[gl * 2], i1 = iv[gl * 2 + 1];
    float t[8];
    t[0] = nv * acc[0] + 0.1f * i0.x; t[1] = nv * acc[1] + 0.1f * i0.y;
    t[2] = nv * acc[2] + 0.1f * i0.z; t[3] = nv * acc[3] + 0.1f * i0.w;
    t[4] = nv * acc[4] + 0.1f * i1.x; t[5] = nv * acc[5] + 0.1f * i1.y;
    t[6] = nv * acc[6] + 0.1f * i1.z; t[7] = nv * acc[7] + 0.1f * i1.w;
    uint4 o;
    o.x = f2bf(t[0]) | ((unsigned)f2bf(t[1]) << 16);
    o.y = f2bf(t[2]) | ((unsigned)f2bf(t[3]) << 16);
    o.z = f2bf(t[4]) | ((unsigned)f2bf(t[5]) << 16);
    o.w = f2bf(t[6]) | ((unsigned)f2bf(t[7]) << 16);
    tb[(size_t)g * 16 + gl] = o;
}

// ===========================================================================
// GEMM: out = relu(t @ M^T), M = 0.5*W + 0.5*I, bf16 MFMA, swizzled LDS.
// ===========================================================================
__device__ __forceinline__ void stage_M(const float* __restrict__ W,
                                        uint4* __restrict__ sMt, int tid) {
    for (int c = tid; c < D * 16; c += THREADS) {
        const int j = c >> 4, kc = c & 15;
        const float* wr = W + j * D + kc * 8;
        float m[8];
#pragma unroll
        for (int q = 0; q < 8; ++q) m[q] = 0.5f * wr[q];
        const int dj = j - kc * 8;
        if (dj >= 0 && dj < 8) m[dj] += 0.5f;   // + 0.5*I
        uint4 o;
        o.x = f2bf(m[0]) | ((unsigned)f2bf(m[1]) << 16);
        o.y = f2bf(m[2]) | ((unsigned)f2bf(m[3]) << 16);
        o.z = f2bf(m[4]) | ((unsigned)f2bf(m[5]) << 16);
        o.w = f2bf(m[6]) | ((unsigned)f2bf(m[7]) << 16);
        sMt[j * 16 + (kc ^ (j & 7))] = o;
    }
}

__device__ __forceinline__ void gemm_tile(const uint4* __restrict__ sMt,
                                          const uint4* __restrict__ sT,
                                          float* __restrict__ out,
                                          int base, int n, int lane, int wave) {
    const int l15 = lane & 15, lq = lane >> 4;
    const int mt = wave & 1, ntb = (wave >> 1) * 4;
    const int nr = mt * 16 + l15;
    s16x8 a[4];
#pragma unroll
    for (int ks = 0; ks < 4; ++ks)
        a[ks] = *reinterpret_cast<const s16x8*>(
            &sT[nr * 16 + ((ks * 4 + lq) ^ (nr & 7))]);

#pragma unroll
    for (int tnt = 0; tnt < 4; ++tnt) {
        const int nt = ntb + tnt;
        const int jr = nt * 16 + l15;
        f32x4 c = {0.f, 0.f, 0.f, 0.f};
#pragma unroll
        for (int ks = 0; ks < 4; ++ks) {
            const s16x8 b = *reinterpret_cast<const s16x8*>(
                &sMt[jr * 16 + ((ks * 4 + lq) ^ (jr & 7))]);
            c = __builtin_amdgcn_mfma_f32_16x16x32_bf16(a[ks], b, c, 0, 0, 0);
        }
        const int col = nt * 16 + l15;
        const int row0 = base + mt * 16 + lq * 4;
#pragma unroll
        for (int r = 0; r < 4; ++r) {
            const int node = row0 + r;
            if (node < n) out[(size_t)node * D + col] = fmaxf(c[r], 0.f);
        }
    }
}

__global__ __launch_bounds__(THREADS) void k_gemm_tb(
    const float* __restrict__ W, const uint4* __restrict__ tb,
    float* __restrict__ out, int n, int numTiles) {
    __shared__ uint4 sMt[D * 16];   // 32 KB
    __shared__ uint4 sT[32 * 16];   // 8 KB
    const int tid = threadIdx.x;
    stage_M(W, sMt, tid);
    __syncthreads();

    const int sn = tid >> 3;
    const int c0 = (tid & 7) * 2;
    const int wave = tid >> 6, lane = tid & 63;

    for (int tile = blockIdx.x; tile < numTiles; tile += gridDim.x) {
        const int base = tile << 5;
        {
            const int node = base + sn;
#pragma unroll
            for (int s = 0; s < 2; ++s) {
                const int cc = c0 + s;
                uint4 o;
                if (node < n) o = tb[(size_t)node * 16 + cc];
                else o.x = o.y = o.z = o.w = 0u;
                sT[sn * 16 + (cc ^ (sn & 7))] = o;
            }
        }
        __syncthreads();
        gemm_tile(sMt, sT, out, base, n, lane, wave);
        __syncthreads();
    }
}

// ===========================================================================
// Fallback tier (small ws or n > MAXB*BS): chain build + fp32 gather + gemm.
// ===========================================================================
__global__ __launch_bounds__(THREADS) void k_build1(
    const int* __restrict__ src, const int* __restrict__ dst,
    int* __restrict__ head, int2* __restrict__ p, int E) {
    int e = blockIdx.x * THREADS + threadIdx.x;
    if (e < E) {
        int nx = atomicExch(&head[dst[e]], e);
        p[e] = make_int2(nx, src[e]);
    }
}

__global__ __launch_bounds__(THREADS) void k_normwalk1(
    const int* __restrict__ head, const int2* __restrict__ p,
    float* __restrict__ normf, int n) {
    int i = blockIdx.x * THREADS + threadIdx.x;
    if (i >= n) return;
    int c = head[i], cnt = 0;
    while (c >= 0) { ++cnt; c = p[c].x; }
    normf[i] = rsqrtf(fmaxf((float)cnt, 1.0f));
}

__global__ __launch_bounds__(THREADS) void k_gatherchain(
    const float* __restrict__ features, const float* __restrict__ initf,
    const int* __restrict__ head, const int2* __restrict__ p,
    const float* __restrict__ normf, float* __restrict__ out, int n) {
    const int g = (blockIdx.x * THREADS + threadIdx.x) >> 4;
    if (g >= n) return;
    const int gl = threadIdx.x & 15;
    float acc[8] = {0.f, 0.f, 0.f, 0.f, 0.f, 0.f, 0.f, 0.f};
    int c = head[g];
    while (c >= 0) {
        const int2 pc = p[c];
        const float w = normf[pc.y];
        const float4* fr = (const float4*)(features + (size_t)pc.y * D);
        const float4 f0 = fr[gl * 2], f1 = fr[gl * 2 + 1];
        acc[0] += f0.x * w; acc[1] += f0.y * w;
        acc[2] += f0.z * w; acc[3] += f0.w * w;
        acc[4] += f1.x * w; acc[5] += f1.y * w;
        acc[6] += f1.z * w; acc[7] += f1.w * w;
        c = pc.x;
    }
    const float nv = 0.9f * normf[g];
    const float4* iv = (const float4*)(initf + (size_t)g * D);
    const float4 i0 = iv[gl * 2], i1 = iv[gl * 2 + 1];
    float4 t0, t1;
    t0.x = nv * acc[0] + 0.1f * i0.x; t0.y = nv * acc[1] + 0.1f * i0.y;
    t0.z = nv * acc[2] + 0.1f * i0.z; t0.w = nv * acc[3] + 0.1f * i0.w;
    t1.x = nv * acc[4] + 0.1f * i1.x; t1.y = nv * acc[5] + 0.1f * i1.y;
    t1.z = nv * acc[6] + 0.1f * i1.z; t1.w = nv * acc[7] + 0.1f * i1.w;
    float4* orow = (float4*)(out + (size_t)g * D);
    orow[gl * 2] = t0;
    orow[gl * 2 + 1] = t1;
}

__global__ __launch_bounds__(THREADS) void k_gemm_ip(
    const float* __restrict__ W, float* __restrict__ out, int n, int numTiles) {
    __shared__ uint4 sMt[D * 16];
    __shared__ uint4 sT[32 * 16];
    const int tid = threadIdx.x;
    stage_M(W, sMt, tid);
    __syncthreads();
    const int sn = tid >> 3;
    const int c0 = (tid & 7) * 2;
    const int wave = tid >> 6, lane = tid & 63;
    for (int tile = blockIdx.x; tile < numTiles; tile += gridDim.x) {
        const int base = tile << 5;
        {
            const int node = base + sn;
#pragma unroll
            for (int s = 0; s < 2; ++s) {
                const int cc = c0 + s;
                uint4 o;
                if (node < n) {
                    const float4* tr = (const float4*)(out + (size_t)node * D);
                    const float4 a = tr[cc * 2], b = tr[cc * 2 + 1];
                    o.x = f2bf(a.x) | ((unsigned)f2bf(a.y) << 16);
                    o.y = f2bf(a.z) | ((unsigned)f2bf(a.w) << 16);
                    o.z = f2bf(b.x) | ((unsigned)f2bf(b.y) << 16);
                    o.w = f2bf(b.z) | ((unsigned)f2bf(b.w) << 16);
                } else {
                    o.x = o.y = o.z = o.w = 0u;
                }
                sT[sn * 16 + (cc ^ (sn & 7))] = o;
            }
        }
        __syncthreads();
        gemm_tile(sMt, sT, out, base, n, lane, wave);
        __syncthreads();
    }
}

// ===========================================================================
extern "C" void kernel_launch(void* const* d_in, const int* in_sizes, int n_in,
                              void* d_out, int out_size, void* d_ws, size_t ws_size,
                              hipStream_t stream) {
    const float* features = (const float*)d_in[0];
    const float* initf    = (const float*)d_in[1];
    const float* W        = (const float*)d_in[2];
    const int*   src      = (const int*)d_in[3];
    const int*   dst      = (const int*)d_in[4];
    float* out = (float*)d_out;

    const int n = in_sizes[0] / D;
    const int E = in_sizes[3];
    if (n <= 0) return;

    const int nbuck = (n + BS - 1) / BS;
    const int numTiles = (n + 31) >> 5;
    const int gridT = numTiles < 1024 ? numTiles : 1024;
    const int gridG = (int)(((size_t)n * 16 + THREADS - 1) / THREADS);

    // workspace layout (16B-aligned slots)
    const size_t nA   = ((size_t)n * 4 + 15) & ~(size_t)15;       // normf
    const size_t oA   = ((size_t)(n + 1) * 4 + 15) & ~(size_t)15; // off
    const size_t bA   = ((size_t)(MAXB + 1) * 4 + 15) & ~(size_t)15;
    const size_t eA   = ((size_t)E * 8 + 15) & ~(size_t)15;       // ebuf
    const size_t cA   = ((size_t)E * 4 + 15) & ~(size_t)15;       // csr
    const size_t hbA  = (size_t)n * 256;                          // hb bf16 rows
    const size_t tbA  = (size_t)n * 256;                          // tb bf16 rows
    const size_t needMain = nA + oA + 3 * bA + eA + cA + hbA + tbA;

    if (nbuck <= MAXB && ws_size >= needMain) {
        char* w = (char*)d_ws;
        float* normf = (float*)w;                 w += nA;
        int*   off   = (int*)w;                   w += oA;
        int*   bcnt  = (int*)w;                   w += bA;
        int*   bbase = (int*)w;                   w += bA;
        int*   bcur  = (int*)w;                   w += bA;
        int2*  ebuf  = (int2*)w;                  w += eA;
        int*   csr   = (int*)w;                   w += cA;
        uint4* hb    = (uint4*)w;                 w += hbA;
        uint4* tb    = (uint4*)w;

        hipMemsetAsync(bcnt, 0, (size_t)(MAXB + 1) * 4, stream);
        k_hist<<<256, THREADS, 0, stream>>>(dst, bcnt, E, nbuck);
        k_scan<<<1, MAXB, 0, stream>>>(bcnt, bbase, bcur, nbuck);
        k_bin<<<(E + BIN_CHUNK - 1) / BIN_CHUNK, BIN_T, 0, stream>>>(
            src, dst, bcur, ebuf, E, nbuck);
        k_csr<<<nbuck, BS, 0, stream>>>(bbase, ebuf, csr, off, normf, n, nbuck);
        k_scale<<<(n * 16 + THREADS - 1) / THREADS, THREADS, 0, stream>>>(
            features, normf, hb, n);
        k_gather_csr<<<gridG, THREADS, 0, stream>>>(hb, initf, off, csr, normf, tb, n);
        k_gemm_tb<<<gridT, THREADS, 0, stream>>>(W, tb, out, n, numTiles);
    } else {
        // fallback: chain build + fp32 gather (t staged in out) + in-place gemm
        const size_t pA = ((size_t)E * 8 + 15) & ~(size_t)15;
        float* normf = (float*)d_ws;
        int*   head  = (int*)((char*)d_ws + nA);
        int2*  p     = (int2*)((char*)d_ws + 2 * nA);
        if (ws_size < 2 * nA + pA) return;
        hipMemsetAsync(head, 0xFF, (size_t)n * 4, stream);
        k_build1<<<(E + THREADS - 1) / THREADS, THREADS, 0, stream>>>(src, dst, head, p, E);
        k_normwalk1<<<(n + THREADS - 1) / THREADS, THREADS, 0, stream>>>(head, p, normf, n);
        k_gatherchain<<<gridG, THREADS, 0, stream>>>(features, initf, head, p, normf, out, n);
        k_gemm_ip<<<gridT, THREADS, 0, stream>>>(W, out, n, numTiles);
    }
}